// Round 12
// baseline (1461.729 us; speedup 1.0000x reference)
//
#include <hip/hip_runtime.h>
#include <math.h>

#define NTHR 1024   // threads per block; 2 threads per point
#define DD   128
#define SELP 80     // float offset of half-1 in padded s_sel (disjoint banks; R11: conflicts -> 0)
#define SLOTS 8     // ull stride per partial slot  (one 64-B line each: no writer ping-pong)
#define BCS   16    // ull stride per bcast replica (one 128-B line each)
#define NBC   8     // bcast replicas; block b polls replica b>>5 (<=32 pollers/line)

typedef unsigned long long ull;

#define FOR8(M) M(0) M(1) M(2) M(3) M(4) M(5) M(6) M(7)

__device__ __forceinline__ ull pkkey(float f, unsigned idx) {
  unsigned u = __float_as_uint(f);
  u = (u & 0x80000000u) ? ~u : (u | 0x80000000u);
  return ((ull)u << 32) | (ull)(~idx);
}

__device__ __forceinline__ ull wredmax(ull v) {
#pragma unroll
  for (int m = 32; m; m >>= 1) {
    ull o = __shfl_xor(v, m, 64);
    v = (o > v) ? o : v;
  }
  return v;
}

// two-hop broadcast sync, latency-trimmed:
//  B1 -> wave0 reduces s_w + lane0 stores own slot (padded line, relaxed)
//  block0 wave0: gather 256 slots (4/lane, pipelined tag poll) -> butterfly ->
//                lanes 0..7 store 8 bcast replicas -> lane0 writes s_far
//  other blocks: tid0 polls its replica -> s_far.  B2.
__device__ __forceinline__ int roundSync(float val, unsigned pidx, int t,
                                         ull* __restrict__ partials,
                                         ull* __restrict__ bcast, int nblk,
                                         ull* s_w, int* s_far,
                                         int tid, int lane, int wid, int blockId) {
  ull key = wredmax(pkkey(val, pidx));
  if (lane == 0) s_w[wid] = key;
  __syncthreads();                                    // B1
  const unsigned tag = (unsigned)(t + 1);
  if (tid < 64) {
    ull m = (lane < NTHR / 64) ? s_w[lane] : 0ull;
    m = wredmax(m);
    if (lane == 0) {
      unsigned idx = ~(unsigned)m;
      ull slotv = (m & 0xFFFFFFFF00000000ull) | ((ull)tag << 17) | (ull)idx;
      __hip_atomic_store(&partials[((t & 1) * nblk + blockId) * SLOTS], slotv,
                         __ATOMIC_RELAXED, __HIP_MEMORY_SCOPE_AGENT);
    }
  }
  if (blockId == 0) {
    if (tid < 64) {
      ull* base = partials + (size_t)(t & 1) * nblk * SLOTS;
      ull r0 = 0, r1 = 0, r2 = 0, r3 = 0;
      unsigned got = 0;
      do {
        if (!(got & 1u)) { r0 = __hip_atomic_load(&base[(tid)       * SLOTS], __ATOMIC_RELAXED, __HIP_MEMORY_SCOPE_AGENT); if (((unsigned)(r0 >> 17) & 0x7FFFu) == tag) got |= 1u; }
        if (!(got & 2u)) { r1 = __hip_atomic_load(&base[(tid +  64) * SLOTS], __ATOMIC_RELAXED, __HIP_MEMORY_SCOPE_AGENT); if (((unsigned)(r1 >> 17) & 0x7FFFu) == tag) got |= 2u; }
        if (!(got & 4u)) { r2 = __hip_atomic_load(&base[(tid + 128) * SLOTS], __ATOMIC_RELAXED, __HIP_MEMORY_SCOPE_AGENT); if (((unsigned)(r2 >> 17) & 0x7FFFu) == tag) got |= 4u; }
        if (!(got & 8u)) { r3 = __hip_atomic_load(&base[(tid + 192) * SLOTS], __ATOMIC_RELAXED, __HIP_MEMORY_SCOPE_AGENT); if (((unsigned)(r3 >> 17) & 0x7FFFu) == tag) got |= 8u; }
      } while (got != 0xFu);
      ull k0 = (r0 & 0xFFFFFFFF00000000ull) | (ull)(~((unsigned)r0 & 0x1FFFFu));
      ull k1 = (r1 & 0xFFFFFFFF00000000ull) | (ull)(~((unsigned)r1 & 0x1FFFFu));
      ull k2 = (r2 & 0xFFFFFFFF00000000ull) | (ull)(~((unsigned)r2 & 0x1FFFFu));
      ull k3 = (r3 & 0xFFFFFFFF00000000ull) | (ull)(~((unsigned)r3 & 0x1FFFFu));
      ull ck = k0 > k1 ? k0 : k1;
      ull ck2 = k2 > k3 ? k2 : k3;
      ck = ck > ck2 ? ck : ck2;
      ck = wredmax(ck);                 // all 64 lanes now hold the winner
      unsigned widx = ~(unsigned)ck;
      ull bv = ((ull)tag << 17) | (ull)widx;
      if (lane < NBC)
        __hip_atomic_store(&bcast[((t & 1) * NBC + lane) * BCS], bv,
                           __ATOMIC_RELAXED, __HIP_MEMORY_SCOPE_AGENT);
      if (lane == 0) *s_far = (int)widx;
    }
  } else {
    if (tid == 0) {
      ull* line = &bcast[((t & 1) * NBC + (blockId >> 5)) * BCS];
      ull v;
      do {
        v = __hip_atomic_load(line, __ATOMIC_RELAXED, __HIP_MEMORY_SCOPE_AGENT);
      } while (((unsigned)(v >> 17) & 0x7FFFu) != tag);
      *s_far = (int)((unsigned)v & 0x1FFFFu);
    }
  }
  __syncthreads();                                    // B2
  return *s_far;
}

// 1-barrier stage: the 64 sumsq lanes hold both halves; after the butterfly
// every lane has the norm, so they write both s_sel entries directly.
__device__ __forceinline__ void stage(const float* __restrict__ feat, int c,
                                      float* s_sel, int tid, int lane) {
  if (tid < 64) {
    const float* __restrict__ row = feat + (size_t)c * DD;
    float x1 = row[lane], x2 = row[lane + 64];
    double s = (double)(x1 * x1) + (double)(x2 * x2);
#pragma unroll
    for (int m = 32; m; m >>= 1) s += __shfl_xor(s, m, 64);
    float nm = fmaxf(sqrtf((float)s), 1e-12f);
    s_sel[lane] = x1 / nm;              // IEEE f32 div: matches reference rounding
    s_sel[SELP + lane] = x2 / nm;
  }
  __syncthreads();
}

__global__ __launch_bounds__(NTHR, 4)
void fps_kernel(const float* __restrict__ feat, const float* __restrict__ att,
                const int* __restrict__ kptr, int* __restrict__ out,
                ull* __restrict__ partials, ull* __restrict__ bcast,
                int N, int nblk) {
  __shared__ float4 s_tile[8][NTHR];    // unit-major stash (R10: conflict-free)
  __shared__ ull s_w[NTHR / 64];
  __shared__ alignas(16) float s_sel[144];
  __shared__ int s_far;

  const int tid  = threadIdx.x;
  const int lane = tid & 63;
  const int wid  = tid >> 6;
  const int gid  = blockIdx.x * NTHR + tid;
  const int pidx = gid >> 1;
  const int half = tid & 1;
  const int k    = kptr[0];

  if (k >= N) {
    for (int i = gid; i < N; i += nblk * NTHR) out[i] = i;
    return;
  }

  const float4* __restrict__ qb = reinterpret_cast<const float4*>(feat + (size_t)gid * 64);
  float4 v0 = qb[0], v1 = qb[1], v2 = qb[2],  v3 = qb[3],
         v4 = qb[4], v5 = qb[5], v6 = qb[6],  v7 = qb[7];
  float4 q0 = qb[8], q1 = qb[9], q2 = qb[10], q3 = qb[11],
         q4 = qb[12], q5 = qb[13], q6 = qb[14], q7 = qb[15];

  {
    double a0 = 0.0, a1 = 0.0, a2 = 0.0, a3 = 0.0;
#define NACC(i) a0 += (double)(v##i.x * v##i.x) + (double)(q##i.x * q##i.x); \
                a1 += (double)(v##i.y * v##i.y) + (double)(q##i.y * q##i.y); \
                a2 += (double)(v##i.z * v##i.z) + (double)(q##i.z * q##i.z); \
                a3 += (double)(v##i.w * v##i.w) + (double)(q##i.w * q##i.w);
    FOR8(NACC)
#undef NACC
    double s = (a0 + a1) + (a2 + a3);
    s += __shfl_xor(s, 1, 64);          // combine pair halves (exact)
    float nm = fmaxf(sqrtf((float)s), 1e-12f);
#define DIVV(i) v##i.x /= nm; v##i.y /= nm; v##i.z /= nm; v##i.w /= nm; \
                q##i.x /= nm; q##i.y /= nm; q##i.z /= nm; q##i.w /= nm; \
    asm volatile("" : "+v"(q##i.x), "+v"(q##i.y), "+v"(q##i.z), "+v"(q##i.w));
    FOR8(DIVV)
#undef DIVV
  }

#define STASH(i) s_tile[i][tid] = v##i;
  FOR8(STASH)
#undef STASH

  int far = roundSync(att[pidx], (unsigned)pidx, 0, partials, bcast, nblk,
                      s_w, &s_far, tid, lane, wid, blockIdx.x);
  if (gid == 0) out[0] = far;

#define DACC_L(i) { float4 a = s_tile[i][tid]; float4 c = sc[i]; \
    float dx = a.x - c.x, dy = a.y - c.y, dz = a.z - c.z, dw = a.w - c.w; \
    b0 += (double)(dx * dx); b1 += (double)(dy * dy); \
    b2 += (double)(dz * dz); b3 += (double)(dw * dw); }
#define DACC_R(i) { float4 c = sc[8 + i]; \
    float dx = q##i.x - c.x, dy = q##i.y - c.y, dz = q##i.z - c.z, dw = q##i.w - c.w; \
    b0 += (double)(dx * dx); b1 += (double)(dy * dy); \
    b2 += (double)(dz * dz); b3 += (double)(dw * dw); }
#define DIST_TO(dvar) do { \
    const float4* sc = reinterpret_cast<const float4*>(s_sel + half * SELP); \
    double b0 = 0.0, b1 = 0.0, b2 = 0.0, b3 = 0.0; \
    FOR8(DACC_L) \
    FOR8(DACC_R) \
    double ss = (b0 + b1) + (b2 + b3); \
    ss += __shfl_xor(ss, 1, 64); \
    dvar = sqrtf((float)ss); \
  } while (0)

  stage(feat, far, s_sel, tid, lane);
  float mind;
  DIST_TO(mind);
  if (pidx == far) mind = -__builtin_inff();

  for (int t = 1; t < k; ++t) {
    far = roundSync(mind, (unsigned)pidx, t, partials, bcast, nblk,
                    s_w, &s_far, tid, lane, wid, blockIdx.x);
    if (gid == 0) out[t] = far;

    stage(feat, far, s_sel, tid, lane);
    float d;
    DIST_TO(d);
    mind = fminf(mind, d);
    if (pidx == far) mind = -__builtin_inff();
  }
}

extern "C" void kernel_launch(void* const* d_in, const int* in_sizes, int n_in,
                              void* d_out, int out_size, void* d_ws, size_t ws_size,
                              hipStream_t stream) {
  const float* feat = (const float*)d_in[0];
  const float* att  = (const float*)d_in[1];
  const int*   kptr = (const int*)d_in[2];
  int* out = (int*)d_out;

  const int N    = in_sizes[1];        // 131072
  const int nblk = (2 * N) / NTHR;     // 256 blocks, 1 per CU, all co-resident

  unsigned char* ws = (unsigned char*)d_ws;
  ull* partials = (ull*)ws;                       // 2 * 256 * 64 B = 32 KB
  ull* bcast    = (ull*)(ws + 2 * 256 * 64);      // 16 replicas * 128 B = 2 KB

  (void)hipMemsetAsync(d_ws, 0, 2 * 256 * 64 + 2048, stream);  // graph-replay determinism
  fps_kernel<<<nblk, NTHR, 0, stream>>>(feat, att, kptr, out, partials, bcast, N, nblk);
}

// Round 13
// 1344.211 us; speedup vs baseline: 1.0874x; 1.0874x over previous
//
#include <hip/hip_runtime.h>
#include <math.h>

#define NTHR 1024   // threads per block; 2 threads per point
#define DD   128
#define SELP 80     // float offset of half-1 in padded s_sel (disjoint banks; R11: conflicts -> 0)

typedef unsigned long long ull;

#define FOR8(M) M(0) M(1) M(2) M(3) M(4) M(5) M(6) M(7)

__device__ __forceinline__ ull pkkey(float f, unsigned idx) {
  unsigned u = __float_as_uint(f);
  u = (u & 0x80000000u) ? ~u : (u | 0x80000000u);
  return ((ull)u << 32) | (ull)(~idx);
}

__device__ __forceinline__ ull wredmax(ull v) {
#pragma unroll
  for (int m = 32; m; m >>= 1) {
    ull o = __shfl_xor(v, m, 64);
    v = (o > v) ? o : v;
  }
  return v;
}

// ============ two-hop broadcast sync (R9/R11-validated; best measured) =======
// Leaders store tagged self-contained slots (relaxed, densely packed -- R12
// showed padding slots to own lines REGRESSES the block0 gather); block0's 256
// threads gather+reduce and publish the winner to ONE bcast line; one thread
// per other block polls that line. R10: flat all-gather regresses (poller
// storm). R12: wave-gather + replicated bcast regress.
__device__ __forceinline__ int roundSyncC(float val, unsigned pidx, int t,
                                          ull* __restrict__ partials,
                                          ull* __restrict__ bcast, int nblk,
                                          ull* s_w, int* s_far,
                                          int tid, int lane, int wid, int blockId) {
  ull key = wredmax(pkkey(val, pidx));
  if (lane == 0) s_w[wid] = key;
  __syncthreads();
  const unsigned tag = (unsigned)(t + 1);
  if (tid == 0) {
    ull m = s_w[0];
#pragma unroll
    for (int i = 1; i < NTHR / 64; ++i) { ull o = s_w[i]; if (o > m) m = o; }
    unsigned idx = ~(unsigned)m;
    ull slotv = (m & 0xFFFFFFFF00000000ull) | ((ull)tag << 17) | (ull)idx;
    __hip_atomic_store(&partials[(t & 1) * nblk + blockId], slotv,
                       __ATOMIC_RELAXED, __HIP_MEMORY_SCOPE_AGENT);
  }
  if (blockId == 0) {
    ull ck = 0;
    if (tid < nblk) {
      ull* slot = &partials[(t & 1) * nblk + tid];
      ull v;
      do {
        v = __hip_atomic_load(slot, __ATOMIC_RELAXED, __HIP_MEMORY_SCOPE_AGENT);
      } while (((unsigned)(v >> 17) & 0x7FFFu) != tag);
      ck = (v & 0xFFFFFFFF00000000ull) | (ull)(~((unsigned)v & 0x1FFFFu));
    }
    ck = wredmax(ck);
    __syncthreads();              // tid0 done reading s_w from argmax phase
    if (lane == 0) s_w[wid] = ck;
    __syncthreads();
    if (tid == 0) {
      ull m = s_w[0];
#pragma unroll
      for (int i = 1; i < NTHR / 64; ++i) { ull o = s_w[i]; if (o > m) m = o; }
      unsigned widx = ~(unsigned)m;
      __hip_atomic_store(&bcast[t & 1], ((ull)tag << 17) | (ull)widx,
                         __ATOMIC_RELAXED, __HIP_MEMORY_SCOPE_AGENT);
      *s_far = (int)widx;
    }
    __syncthreads();
  } else {
    if (tid == 0) {
      ull v;
      do {
        v = __hip_atomic_load(&bcast[t & 1], __ATOMIC_RELAXED, __HIP_MEMORY_SCOPE_AGENT);
      } while (((unsigned)(v >> 17) & 0x7FFFu) != tag);
      *s_far = (int)((unsigned)v & 0x1FFFFu);
    }
    __syncthreads();
  }
  return *s_far;
}

// 1-barrier stage (R12-validated correct): the 64 sumsq lanes hold both row
// halves; after the butterfly every lane has the norm and writes both padded
// s_sel entries directly. Saves a __syncthreads + s_nrm roundtrip vs R11.
__device__ __forceinline__ void stage(const float* __restrict__ feat, int c,
                                      float* s_sel, int tid, int lane) {
  if (tid < 64) {
    const float* __restrict__ row = feat + (size_t)c * DD;
    float x1 = row[lane], x2 = row[lane + 64];
    double s = (double)(x1 * x1) + (double)(x2 * x2);
#pragma unroll
    for (int m = 32; m; m >>= 1) s += __shfl_xor(s, m, 64);
    float nm = fmaxf(sqrtf((float)s), 1e-12f);
    s_sel[lane] = x1 / nm;              // IEEE f32 div: matches reference rounding
    s_sel[SELP + lane] = x2 / nm;
  }
  __syncthreads();
}

__global__ __launch_bounds__(NTHR, 4)
void fps_kernel(const float* __restrict__ feat, const float* __restrict__ att,
                const int* __restrict__ kptr, int* __restrict__ out,
                ull* __restrict__ partials, ull* __restrict__ bcast,
                int N, int nblk) {
  __shared__ float4 s_tile[8][NTHR];    // unit-major stash (R10: conflict-free)
  __shared__ ull s_w[NTHR / 64];
  __shared__ alignas(16) float s_sel[144];   // 64 + 16 pad + 64
  __shared__ int s_far;

  const int tid  = threadIdx.x;
  const int lane = tid & 63;
  const int wid  = tid >> 6;
  const int gid  = blockIdx.x * NTHR + tid;
  const int pidx = gid >> 1;
  const int half = tid & 1;
  const int k    = kptr[0];

  if (k >= N) {
    for (int i = gid; i < N; i += nblk * NTHR) out[i] = i;
    return;
  }

  const float4* __restrict__ qb = reinterpret_cast<const float4*>(feat + (size_t)gid * 64);
  float4 v0 = qb[0], v1 = qb[1], v2 = qb[2],  v3 = qb[3],
         v4 = qb[4], v5 = qb[5], v6 = qb[6],  v7 = qb[7];
  float4 q0 = qb[8], q1 = qb[9], q2 = qb[10], q3 = qb[11],
         q4 = qb[12], q5 = qb[13], q6 = qb[14], q7 = qb[15];

  {
    double a0 = 0.0, a1 = 0.0, a2 = 0.0, a3 = 0.0;
#define NACC(i) a0 += (double)(v##i.x * v##i.x) + (double)(q##i.x * q##i.x); \
                a1 += (double)(v##i.y * v##i.y) + (double)(q##i.y * q##i.y); \
                a2 += (double)(v##i.z * v##i.z) + (double)(q##i.z * q##i.z); \
                a3 += (double)(v##i.w * v##i.w) + (double)(q##i.w * q##i.w);
    FOR8(NACC)
#undef NACC
    double s = (a0 + a1) + (a2 + a3);
    s += __shfl_xor(s, 1, 64);          // combine pair halves (exact)
    float nm = fmaxf(sqrtf((float)s), 1e-12f);
    // IEEE f32 divide (matches reference elementwise rounding); pin reg half
#define DIVV(i) v##i.x /= nm; v##i.y /= nm; v##i.z /= nm; v##i.w /= nm; \
                q##i.x /= nm; q##i.y /= nm; q##i.z /= nm; q##i.w /= nm; \
    asm volatile("" : "+v"(q##i.x), "+v"(q##i.y), "+v"(q##i.z), "+v"(q##i.w));
    FOR8(DIVV)
#undef DIVV
  }

#define STASH(i) s_tile[i][tid] = v##i;
  FOR8(STASH)
#undef STASH

  int far = roundSyncC(att[pidx], (unsigned)pidx, 0, partials, bcast, nblk,
                       s_w, &s_far, tid, lane, wid, blockIdx.x);
  if (gid == 0) out[0] = far;

#define DACC_L(i) { float4 a = s_tile[i][tid]; float4 c = sc[i]; \
    float dx = a.x - c.x, dy = a.y - c.y, dz = a.z - c.z, dw = a.w - c.w; \
    b0 += (double)(dx * dx); b1 += (double)(dy * dy); \
    b2 += (double)(dz * dz); b3 += (double)(dw * dw); }
#define DACC_R(i) { float4 c = sc[8 + i]; \
    float dx = q##i.x - c.x, dy = q##i.y - c.y, dz = q##i.z - c.z, dw = q##i.w - c.w; \
    b0 += (double)(dx * dx); b1 += (double)(dy * dy); \
    b2 += (double)(dz * dz); b3 += (double)(dw * dw); }
#define DIST_TO(dvar) do { \
    const float4* sc = reinterpret_cast<const float4*>(s_sel + half * SELP); \
    double b0 = 0.0, b1 = 0.0, b2 = 0.0, b3 = 0.0; \
    FOR8(DACC_L) \
    FOR8(DACC_R) \
    double ss = (b0 + b1) + (b2 + b3); \
    ss += __shfl_xor(ss, 1, 64); \
    dvar = sqrtf((float)ss); \
  } while (0)

  stage(feat, far, s_sel, tid, lane);
  float mind;
  DIST_TO(mind);
  if (pidx == far) mind = -__builtin_inff();

  for (int t = 1; t < k; ++t) {
    far = roundSyncC(mind, (unsigned)pidx, t, partials, bcast, nblk,
                     s_w, &s_far, tid, lane, wid, blockIdx.x);
    if (gid == 0) out[t] = far;

    stage(feat, far, s_sel, tid, lane);
    float d;
    DIST_TO(d);
    mind = fminf(mind, d);
    if (pidx == far) mind = -__builtin_inff();
  }
}

extern "C" void kernel_launch(void* const* d_in, const int* in_sizes, int n_in,
                              void* d_out, int out_size, void* d_ws, size_t ws_size,
                              hipStream_t stream) {
  const float* feat = (const float*)d_in[0];
  const float* att  = (const float*)d_in[1];
  const int*   kptr = (const int*)d_in[2];
  int* out = (int*)d_out;

  const int N    = in_sizes[1];        // 131072
  const int nblk = (2 * N) / NTHR;     // 256 blocks, 1 per CU, all co-resident

  unsigned char* ws = (unsigned char*)d_ws;
  ull* partials = (ull*)ws;            // 2*nblk slots = 4 KB (dense -- R12: padding regresses)
  ull* bcast    = (ull*)(ws + 4096);   // 2 broadcast lines

  (void)hipMemsetAsync(d_ws, 0, 8192, stream);  // graph-replay determinism
  fps_kernel<<<nblk, NTHR, 0, stream>>>(feat, att, kptr, out, partials, bcast, N, nblk);
}